// Round 16
// baseline (49.636 us; speedup 1.0000x reference)
//
#include <hip/hip_runtime.h>
#include <hip/hip_bf16.h>

// out[m,u] = sum_t x[m,t] * W_eff[u,t] + b_eff[u]      (m = 32*512 rows)
//   W_eff = Ws + (Wt - Ws) @ A   (A = causal window-mean, window 25)
// Round-16: r13 base (512 thr / 8 waves, BM=64, wave = 64m x 96u, depth-2
// W ring) + CHUNKED X-STREAMING DOUBLE-BUFFER: T split into 5 K-chunks
// (160x4 + 96); while the K-loop consumes chunk c from LDS buf[c&1], the
// next chunk's global loads are in flight (issued before the K-steps) and
// are cvt+ds_written to buf[(c+1)&1] after, then ONE barrier per chunk.
// The x prologue (7.5 us serial in r13) now overlaps the L2-bound K-loop.
// 512 thr -> 256-VGPR budget: acc 96 + ring 72 + stage 20 + misc ~ 239.

#define Tdim  720
#define KP    736      // padded K (23*32); Wb zero-filled for k>=720
#define WROWS 768      // padded u-rows of Wb (zero rows >=720)
#define BM    64
#define LSTR  164      // LDS row stride elems: 82 dw %32=18 -> ~2-way banks

using bf16x8 = __attribute__((ext_vector_type(8))) __bf16;
using bf16x4 = __attribute__((ext_vector_type(4))) __bf16;
using f32x4  = __attribute__((ext_vector_type(4))) float;

__global__ void fold_w_kernel(const float* __restrict__ tw,
                              const float* __restrict__ tb,
                              const float* __restrict__ sw,
                              const float* __restrict__ sb,
                              __bf16* __restrict__ Wb,
                              float* __restrict__ beff) {
  int idx = blockIdx.x * 256 + threadIdx.x;
  if (idx >= WROWS * KP) return;
  int u = idx / KP;
  int i = idx - u * KP;
  float w = 0.0f;
  if (u < Tdim && i < Tdim) {
    const float* twr = tw + (size_t)u * Tdim;
    const float* swr = sw + (size_t)u * Tdim;
    int tend = (i + 25 < Tdim) ? (i + 25) : Tdim;
    float acc = 0.0f;
    if (i >= 24) {
      #pragma unroll 5
      for (int t = i; t < tend; ++t) acc += twr[t] - swr[t];
      acc *= 0.04f;
    } else {
      for (int t = i; t < tend; ++t) {
        float c = (t >= 24) ? 0.04f : 1.0f / (float)(t + 1);
        acc += (twr[t] - swr[t]) * c;
      }
    }
    w = swr[i] + acc;
  }
  Wb[idx] = (__bf16)w;
  if (i == 0 && u < Tdim) beff[u] = tb[u] + sb[u];
}

__global__ __launch_bounds__(512, 2)
void dlinear_gemm(const float* __restrict__ x,
                  const __bf16* __restrict__ Wb,
                  const float* __restrict__ beff,
                  float* __restrict__ out) {
  __shared__ __bf16 As[2][BM * LSTR];   // 2 x 21 KB ping-pong

  const int tid  = threadIdx.x;
  const int lane = tid & 63;
  const int wid  = tid >> 6;          // 0..7
  const int lg = lane >> 4, lr = lane & 15;

  const int m0 = blockIdx.x * BM;
  const int u0 = wid * 96;            // wave owns 96 u-cols (768 = 8*96 padded)

  // ---- W stream pointers; depth-2 ring slot(g) = g%3
  const __bf16* wp[6];
  #pragma unroll
  for (int ni = 0; ni < 6; ++ni)
    wp[ni] = Wb + (size_t)(u0 + ni * 16 + lr) * KP + lg * 8;

  bf16x8 s0[6], s1[6], s2[6];
  #pragma unroll
  for (int ni = 0; ni < 6; ++ni) s0[ni] = *(const bf16x8*)(wp[ni]);        // W0
  #pragma unroll
  for (int ni = 0; ni < 6; ++ni) s1[ni] = *(const bf16x8*)(wp[ni] + 32);   // W1

  // ---- stage chunk 0 (cols 0..159) -> buf0 : 64 rows x 40 col4-units
  #pragma unroll
  for (int i = 0; i < 5; ++i) {
    int unit = tid + 512 * i;
    int row  = unit / 40;
    int c4   = unit - row * 40;
    f32x4 a = *(const f32x4*)(x + (size_t)(m0 + row) * Tdim + c4 * 4);
    bf16x4 v;
    #pragma unroll
    for (int j = 0; j < 4; ++j) v[j] = (__bf16)a[j];
    *(bf16x4*)(&As[0][row * LSTR + c4 * 4]) = v;
  }
  __syncthreads();

  int arofs[4];
  #pragma unroll
  for (int mi = 0; mi < 4; ++mi) arofs[mi] = (mi * 16 + lr) * LSTR + lg * 8;

  f32x4 acc[4][6];
  #pragma unroll
  for (int mi = 0; mi < 4; ++mi)
    #pragma unroll
    for (int ni = 0; ni < 6; ++ni) {
      f32x4 z; z[0] = 0.f; z[1] = 0.f; z[2] = 0.f; z[3] = 0.f;
      acc[mi][ni] = z;
    }

  f32x4 stg[5];                        // stage-ahead regs (static indices)

  // issue loads for chunk C (cols CB..CB+159), 40 col4/row
#define STAGE_ISSUE_FULL(CB)                                                   \
  { _Pragma("unroll")                                                          \
    for (int i = 0; i < 5; ++i) {                                              \
      int unit = tid + 512 * i;                                                \
      int row  = unit / 40;                                                    \
      int c4   = unit - row * 40;                                              \
      stg[i] = *(const f32x4*)(x + (size_t)(m0 + row) * Tdim + (CB) + c4 * 4); \
    } }

  // last chunk: cols 640..735, 24 col4/row; c4>=20 is zero pad (720..735)
#define STAGE_ISSUE_LAST()                                                     \
  { _Pragma("unroll")                                                          \
    for (int i = 0; i < 3; ++i) {                                              \
      int unit = tid + 512 * i;                                                \
      int row  = unit / 24;                                                    \
      int c4   = unit - row * 24;                                              \
      if (c4 < 20)                                                             \
        stg[i] = *(const f32x4*)(x + (size_t)(m0 + row) * Tdim + 640 + c4 * 4);\
      else { f32x4 z; z[0]=0.f; z[1]=0.f; z[2]=0.f; z[3]=0.f; stg[i] = z; }    \
    } }

#define STAGE_WRITE_FULL(BUF)                                                  \
  { _Pragma("unroll")                                                          \
    for (int i = 0; i < 5; ++i) {                                              \
      int unit = tid + 512 * i;                                                \
      int row  = unit / 40;                                                    \
      int c4   = unit - row * 40;                                              \
      bf16x4 v;                                                                \
      _Pragma("unroll")                                                        \
      for (int j = 0; j < 4; ++j) v[j] = (__bf16)stg[i][j];                    \
      *(bf16x4*)(&As[BUF][row * LSTR + c4 * 4]) = v;                           \
    } }

#define STAGE_WRITE_LAST(BUF)                                                  \
  { _Pragma("unroll")                                                          \
    for (int i = 0; i < 3; ++i) {                                              \
      int unit = tid + 512 * i;                                                \
      int row  = unit / 24;                                                    \
      int c4   = unit - row * 24;                                              \
      bf16x4 v;                                                                \
      _Pragma("unroll")                                                        \
      for (int j = 0; j < 4; ++j) v[j] = (__bf16)stg[i][j];                    \
      *(bf16x4*)(&As[BUF][row * LSTR + c4 * 4]) = v;                           \
    } }

  // K-step g (global), local t, buffer B; consume CUR, load W(g+2) into NXT
#define KSTEP(G, TL, B, CUR, NXT, DO_LOAD)                                     \
  { if (DO_LOAD) {                                                             \
      _Pragma("unroll")                                                        \
      for (int ni = 0; ni < 6; ++ni)                                           \
        NXT[ni] = *(const bf16x8*)(wp[ni] + ((G) + 2) * 32);                   \
    }                                                                          \
    bf16x8 av[4];                                                              \
    _Pragma("unroll")                                                          \
    for (int mi = 0; mi < 4; ++mi)                                             \
      av[mi] = *(const bf16x8*)(&As[B][arofs[mi] + (TL) * 32]);                \
    _Pragma("unroll")                                                          \
    for (int mi = 0; mi < 4; ++mi)                                             \
      _Pragma("unroll")                                                        \
      for (int ni = 0; ni < 6; ++ni)                                           \
        acc[mi][ni] = __builtin_amdgcn_mfma_f32_16x16x32_bf16(av[mi],          \
                        CUR[ni], acc[mi][ni], 0, 0, 0);                        \
  }

  // ---- chunk 0: g=0..4, buf0; stage chunk1 in flight
  STAGE_ISSUE_FULL(160)
  KSTEP(0, 0, 0, s0, s2, true)
  KSTEP(1, 1, 0, s1, s0, true)
  KSTEP(2, 2, 0, s2, s1, true)
  KSTEP(3, 3, 0, s0, s2, true)
  KSTEP(4, 4, 0, s1, s0, true)
  STAGE_WRITE_FULL(1)
  __syncthreads();

  // ---- chunk 1: g=5..9, buf1; stage chunk2
  STAGE_ISSUE_FULL(320)
  KSTEP(5, 0, 1, s2, s1, true)
  KSTEP(6, 1, 1, s0, s2, true)
  KSTEP(7, 2, 1, s1, s0, true)
  KSTEP(8, 3, 1, s2, s1, true)
  KSTEP(9, 4, 1, s0, s2, true)
  STAGE_WRITE_FULL(0)
  __syncthreads();

  // ---- chunk 2: g=10..14, buf0; stage chunk3
  STAGE_ISSUE_FULL(480)
  KSTEP(10, 0, 0, s1, s0, true)
  KSTEP(11, 1, 0, s2, s1, true)
  KSTEP(12, 2, 0, s0, s2, true)
  KSTEP(13, 3, 0, s1, s0, true)
  KSTEP(14, 4, 0, s2, s1, true)
  STAGE_WRITE_FULL(1)
  __syncthreads();

  // ---- chunk 3: g=15..19, buf1; stage chunk4 (last)
  STAGE_ISSUE_LAST()
  KSTEP(15, 0, 1, s0, s2, true)
  KSTEP(16, 1, 1, s1, s0, true)
  KSTEP(17, 2, 1, s2, s1, true)
  KSTEP(18, 3, 1, s0, s2, true)
  KSTEP(19, 4, 1, s1, s0, true)
  STAGE_WRITE_LAST(0)
  __syncthreads();

  // ---- chunk 4: g=20..22, buf0 (96 cols incl zero pad)
  KSTEP(20, 0, 0, s2, s1, true)      // loads W22 (last)
  KSTEP(21, 1, 0, s0, s2, false)
  KSTEP(22, 2, 0, s1, s2, false)

#undef KSTEP
#undef STAGE_ISSUE_FULL
#undef STAGE_ISSUE_LAST
#undef STAGE_WRITE_FULL
#undef STAGE_WRITE_LAST

  // ---- epilogue: C/D layout col = lr -> u, row = lg*4 + j -> m
  #pragma unroll
  for (int ni = 0; ni < 6; ++ni) {
    const int u = u0 + ni * 16 + lr;
    if (u >= Tdim) continue;           // pad u-rows (>=720) skipped
    const float bias = beff[u];
    #pragma unroll
    for (int mi = 0; mi < 4; ++mi) {
      const int mb = m0 + mi * 16 + lg * 4;
      #pragma unroll
      for (int j = 0; j < 4; ++j)
        out[(size_t)(mb + j) * Tdim + u] = acc[mi][ni][j] + bias;
    }
  }
}

extern "C" void kernel_launch(void* const* d_in, const int* in_sizes, int n_in,
                              void* d_out, int out_size, void* d_ws, size_t ws_size,
                              hipStream_t stream) {
  const float* x  = (const float*)d_in[0];
  const float* tw = (const float*)d_in[1];
  const float* tb = (const float*)d_in[2];
  const float* sw = (const float*)d_in[3];
  const float* sb = (const float*)d_in[4];
  float* out = (float*)d_out;

  __bf16* Wb  = (__bf16*)d_ws;
  float* beff = (float*)((char*)d_ws + (size_t)WROWS * KP * sizeof(__bf16));

  const int fold_total = WROWS * KP;
  fold_w_kernel<<<dim3((fold_total + 255) / 256), dim3(256), 0, stream>>>(
      tw, tb, sw, sb, Wb, beff);

  const int M = in_sizes[0] / Tdim;            // 16384
  dim3 grid(M / BM);                           // 256 blocks, 1 per CU
  dlinear_gemm<<<grid, dim3(512), 0, stream>>>(x, Wb, beff, out);
}

// Round 17
// 42.035 us; speedup vs baseline: 1.1808x; 1.1808x over previous
//
#include <hip/hip_runtime.h>
#include <hip/hip_bf16.h>

// out[m,u] = sum_t x[m,t] * W_eff[u,t] + b_eff[u]      (m = 32*512 rows)
//   W_eff = Ws + (Wt - Ws) @ A   (A = causal window-mean, window 25)
// Round-17: GEMM = round-11 verbatim (best measured: 41.8 us dispatch).
// FOLD REWRITTEN row-resident: one block per u-row; tw/sw rows loaded once
// (coalesced f32x4) into LDS (D = tw-sw, S = sw); 25-tap window read from
// LDS instead of 50 scalar global loads per output. Global traffic for the
// fold drops 259 MB -> ~5 MB (25x), ~4.9 us -> ~1.2 us.

#define Tdim  720
#define KP    736      // padded K (23*32); Wb zero-filled for k>=720
#define WROWS 768      // padded u-rows of Wb (zero rows >=720)
#define NK    23
#define BM    64       // m-rows per block
#define APAD  744      // LDS row stride in elems

using bf16x8 = __attribute__((ext_vector_type(8))) __bf16;
using f32x4  = __attribute__((ext_vector_type(4))) float;

__global__ __launch_bounds__(256)
void fold_w_kernel(const float* __restrict__ tw,
                   const float* __restrict__ tb,
                   const float* __restrict__ sw,
                   const float* __restrict__ sb,
                   __bf16* __restrict__ Wb,
                   float* __restrict__ beff) {
  __shared__ float D[744];            // tw-sw, zero-padded to i+24 max reach
  __shared__ float S[720];            // sw row

  const int u   = blockIdx.x;         // 0..767
  const int tid = threadIdx.x;

  if (u >= Tdim) {                    // pad rows of Wb: pure zeros
    for (int i = tid; i < KP; i += 256)
      Wb[(size_t)u * KP + i] = (__bf16)0.0f;
    return;
  }

  const float* twr = tw + (size_t)u * Tdim;
  const float* swr = sw + (size_t)u * Tdim;

  for (int j = tid; j < 180; j += 256) {      // 180 f32x4 units = 720 elems
    f32x4 a = ((const f32x4*)twr)[j];
    f32x4 b = ((const f32x4*)swr)[j];
    #pragma unroll
    for (int q = 0; q < 4; ++q) {
      D[j * 4 + q] = a[q] - b[q];
      S[j * 4 + q] = b[q];
    }
  }
  if (tid < 24) D[720 + tid] = 0.0f;          // window over-reach pad
  __syncthreads();

  for (int i = tid; i < KP; i += 256) {
    float w;
    if (i >= Tdim) {
      w = 0.0f;                                // K-pad cols of Wb
    } else {
      float acc = 0.0f;
      if (i >= 24) {
        #pragma unroll
        for (int t = 0; t < 25; ++t) acc += D[i + t];   // D pad makes tail exact
        acc *= 0.04f;
      } else {
        for (int t = i; t < i + 25; ++t) {
          float c = (t >= 24) ? 0.04f : 1.0f / (float)(t + 1);
          acc += D[t] * c;
        }
      }
      w = S[i] + acc;
    }
    Wb[(size_t)u * KP + i] = (__bf16)w;
  }
  if (tid == 0) beff[u] = tb[u] + sb[u];
}

__global__ __launch_bounds__(1024, 1)
void dlinear_gemm(const float* __restrict__ x,
                  const __bf16* __restrict__ Wb,
                  const float* __restrict__ beff,
                  float* __restrict__ out) {
  __shared__ __bf16 As[BM * APAD];   // 95232 B -> 1 block/CU

  const int tid  = threadIdx.x;
  const int lane = tid & 63;
  const int wid  = tid >> 6;          // 0..15
  const int lg = lane >> 4, lr = lane & 15;

  const int m0 = blockIdx.x * BM;
  const int u0 = wid * 48;            // wave owns 48 u-cols (768 = 16*48 padded)

  // ---- prologue: x[m0..m0+64) x [0..720) -> LDS bf16 (coalesced 32B/lane)
  #pragma unroll
  for (int c = 0; c < 6; ++c) {
    int idx = tid + 1024 * c;         // 8-f32 chunk id; 90 chunks per row
    if (idx < BM * 90) {
      int row  = idx / 90;
      int col8 = idx - row * 90;
      const float* p = x + (size_t)(m0 + row) * Tdim + col8 * 8;
      f32x4 a0 = ((const f32x4*)p)[0];
      f32x4 a1 = ((const f32x4*)p)[1];
      bf16x8 v;
      #pragma unroll
      for (int j = 0; j < 4; ++j) { v[j] = (__bf16)a0[j]; v[j + 4] = (__bf16)a1[j]; }
      *(bf16x8*)(&As[row * APAD + col8 * 8]) = v;
    }
  }
  {  // zero the K-pad [720,736): 64 rows x 16 elems = 1024 threads exactly
    int r = tid >> 4;
    int c = 720 + (tid & 15);
    As[r * APAD + c] = (__bf16)0.0f;
  }
  __syncthreads();                    // the ONLY barrier

  // ---- W stream pointers: frag ni -> row u0+ni*16+lr, 16B chunk lg within K-step
  const __bf16* wp[3];
  #pragma unroll
  for (int ni = 0; ni < 3; ++ni)
    wp[ni] = Wb + (size_t)(u0 + ni * 16 + lr) * KP + lg * 8;

  int arofs[4];
  #pragma unroll
  for (int mi = 0; mi < 4; ++mi) arofs[mi] = (mi * 16 + lr) * APAD + lg * 8;

  f32x4 acc[4][3];
  #pragma unroll
  for (int mi = 0; mi < 4; ++mi)
    #pragma unroll
    for (int ni = 0; ni < 3; ++ni) {
      f32x4 z; z[0] = 0.f; z[1] = 0.f; z[2] = 0.f; z[3] = 0.f;
      acc[mi][ni] = z;
    }

  // ---- K-loop: depth-2 W pipeline, 3 named slots, zero barriers.
  bf16x8 s0[3], s1[3], s2[3];
  #pragma unroll
  for (int ni = 0; ni < 3; ++ni) s0[ni] = *(const bf16x8*)(wp[ni]);        // W0
  #pragma unroll
  for (int ni = 0; ni < 3; ++ni) s1[ni] = *(const bf16x8*)(wp[ni] + 32);   // W1

#define GEMM_STEP(T, SLOT, ISSUE_SLOT, DO_ISSUE)                               \
  {                                                                            \
    if (DO_ISSUE) {                                                            \
      _Pragma("unroll")                                                        \
      for (int ni = 0; ni < 3; ++ni)                                           \
        ISSUE_SLOT[ni] = *(const bf16x8*)(wp[ni] + ((T) + 2) * 32);            \
    }                                                                          \
    bf16x8 av[4];                                                              \
    _Pragma("unroll")                                                          \
    for (int mi = 0; mi < 4; ++mi)                                             \
      av[mi] = *(const bf16x8*)(&As[arofs[mi] + (T) * 32]);                    \
    _Pragma("unroll")                                                          \
    for (int mi = 0; mi < 4; ++mi)                                             \
      _Pragma("unroll")                                                        \
      for (int ni = 0; ni < 3; ++ni)                                           \
        acc[mi][ni] = __builtin_amdgcn_mfma_f32_16x16x32_bf16(av[mi],          \
                        SLOT[ni], acc[mi][ni], 0, 0, 0);                       \
  }

  for (int t = 0; t < 21; t += 3) {    // t = 0,3,...,18 (covers 0..20)
    GEMM_STEP(t,     s0, s2, true)     // compute W(t),   issue W(t+2) -> s2
    GEMM_STEP(t + 1, s1, s0, true)     // compute W(t+1), issue W(t+3) -> s0
    GEMM_STEP(t + 2, s2, s1, true)     // compute W(t+2), issue W(t+4) -> s1
  }
  GEMM_STEP(21, s0, s2, false)         // W21 (loaded at t=18 phase b)
  GEMM_STEP(22, s1, s2, false)         // W22 (loaded at t=18 phase c)
#undef GEMM_STEP

  // ---- epilogue: C/D layout col = lr -> u, row = lg*4 + j -> m
  #pragma unroll
  for (int ni = 0; ni < 3; ++ni) {
    const int u = u0 + ni * 16 + lr;
    if (u >= Tdim) continue;
    const float bias = beff[u];
    #pragma unroll
    for (int mi = 0; mi < 4; ++mi) {
      const int mb = m0 + mi * 16 + lg * 4;
      #pragma unroll
      for (int j = 0; j < 4; ++j)
        out[(size_t)(mb + j) * Tdim + u] = acc[mi][ni][j] + bias;
    }
  }
}

extern "C" void kernel_launch(void* const* d_in, const int* in_sizes, int n_in,
                              void* d_out, int out_size, void* d_ws, size_t ws_size,
                              hipStream_t stream) {
  const float* x  = (const float*)d_in[0];
  const float* tw = (const float*)d_in[1];
  const float* tb = (const float*)d_in[2];
  const float* sw = (const float*)d_in[3];
  const float* sb = (const float*)d_in[4];
  float* out = (float*)d_out;

  __bf16* Wb  = (__bf16*)d_ws;
  float* beff = (float*)((char*)d_ws + (size_t)WROWS * KP * sizeof(__bf16));

  fold_w_kernel<<<dim3(WROWS), dim3(256), 0, stream>>>(tw, tb, sw, sb, Wb, beff);

  const int M = in_sizes[0] / Tdim;            // 16384
  dim3 grid(M / BM);                           // 256 blocks, 1 per CU
  dlinear_gemm<<<grid, dim3(1024), 0, stream>>>(x, Wb, beff, out);
}